// Round 1
// baseline (209.463 us; speedup 1.0000x reference)
//
#include <hip/hip_runtime.h>
#include <math.h>

// AttentionAggregator: out[n] = sum_k softmax_k(feats[n,k,:]·w) * feats[n,k,:]
// feats[n,k,:] = embed_table[neigh_idx[n,k], :]
// N=100000, K=10, VOCAB=200000, D=128, all fp32.
//
// Strategy: one 64-lane wave per node. Each lane owns 2 of the 128 dims
// (float2). Each of the K=10 gathers is a single coalesced 512B wave read.
// Dot products via lane-partial FMA + xor-shuffle butterfly (all lanes get
// the full sum, so softmax over K is computed redundantly in-register —
// zero LDS, zero atomics). Fragments stay in registers for the weighted sum.

#define KNEIGH 10
#define DIM 128

__global__ __launch_bounds__(256) void attn_agg_kernel(
    const float* __restrict__ table,
    const float* __restrict__ attn_w,
    const int*   __restrict__ idx,
    float*       __restrict__ out,
    int n_nodes)
{
    const int gtid = blockIdx.x * blockDim.x + threadIdx.x;
    const int node = gtid >> 6;          // one wave per node
    const int lane = threadIdx.x & 63;
    if (node >= n_nodes) return;

    // attention weights: 2 floats per lane (broadcast-cached in L1)
    const float2 wv = *(const float2*)(attn_w + lane * 2);

    // lanes 0..K-1 load the K neighbor indices; broadcast via shuffle
    int my_idx = 0;
    if (lane < KNEIGH) my_idx = idx[node * KNEIGH + lane];

    float2 f[KNEIGH];
    float  s[KNEIGH];

    #pragma unroll
    for (int k = 0; k < KNEIGH; ++k) {
        const int id = __shfl(my_idx, k, 64);
        f[k] = *(const float2*)(table + (size_t)id * DIM + lane * 2);
        float p = f[k].x * wv.x + f[k].y * wv.y;
        // 64-lane butterfly reduce: every lane ends with the full dot product
        #pragma unroll
        for (int off = 32; off >= 1; off >>= 1)
            p += __shfl_xor(p, off, 64);
        s[k] = p;
    }

    // softmax over K (redundant per lane — trivially cheap)
    float m = s[0];
    #pragma unroll
    for (int k = 1; k < KNEIGH; ++k) m = fmaxf(m, s[k]);
    float denom = 0.f;
    #pragma unroll
    for (int k = 0; k < KNEIGH; ++k) { s[k] = __expf(s[k] - m); denom += s[k]; }
    const float inv = 1.0f / denom;

    float2 acc = make_float2(0.f, 0.f);
    #pragma unroll
    for (int k = 0; k < KNEIGH; ++k) {
        const float wk = s[k] * inv;
        acc.x = fmaf(wk, f[k].x, acc.x);
        acc.y = fmaf(wk, f[k].y, acc.y);
    }

    *(float2*)(out + (size_t)node * DIM + lane * 2) = acc;
}

extern "C" void kernel_launch(void* const* d_in, const int* in_sizes, int n_in,
                              void* d_out, int out_size, void* d_ws, size_t ws_size,
                              hipStream_t stream) {
    const float* table  = (const float*)d_in[0];   // [VOCAB, D] fp32
    const float* attn_w = (const float*)d_in[1];   // [D] fp32
    const int*   idx    = (const int*)d_in[2];     // [N, K] int32
    float*       out    = (float*)d_out;           // [N, D] fp32

    const int n_nodes = in_sizes[2] / KNEIGH;
    const int waves_per_block = 4;                 // 256 threads
    const int blocks = (n_nodes + waves_per_block - 1) / waves_per_block;
    attn_agg_kernel<<<blocks, 256, 0, stream>>>(table, attn_w, idx, out, n_nodes);
}